// Round 16
// baseline (216.575 us; speedup 1.0000x reference)
//
#include <hip/hip_runtime.h>

#define D 128
#define N_SCAN 1024
#define BSH 7            // 128 nodes per bin
#define MAXBINS 1024     // supports N <= 131072 (also the src<2^17 packing limit)

typedef float  f32x4  __attribute__((ext_vector_type(4)));
typedef short  s16x8  __attribute__((ext_vector_type(8)));   // 8 bf16 (4 VGPRs)
typedef unsigned short us8 __attribute__((ext_vector_type(8)));

__device__ __forceinline__ unsigned short f2bf(float f) {
    unsigned b = __float_as_uint(f);
    return (unsigned short)((b + 0x7fffu + ((b >> 16) & 1u)) >> 16);  // RTNE
}
__device__ __forceinline__ float bf2f(unsigned short u) {
    return __uint_as_float((unsigned)u << 16);
}

// ===========================================================================
// Binned CSR build (write-locality-friendly counting sort)
// ===========================================================================
__global__ __launch_bounds__(256) void bin_hist(
    const int* __restrict__ dst, int* __restrict__ bincnt, int E, int BINS)
{
    __shared__ int h[MAXBINS];
    for (int b = threadIdx.x; b < BINS; b += 256) h[b] = 0;
    __syncthreads();
    int base = blockIdx.x * 4096;
    #pragma unroll
    for (int j = 0; j < 16; ++j) {
        int e = base + j * 256 + threadIdx.x;
        if (e < E) atomicAdd(&h[dst[e] >> BSH], 1);
    }
    __syncthreads();
    for (int b = threadIdx.x; b < BINS; b += 256)
        if (h[b]) atomicAdd(&bincnt[b], h[b]);
}

// single block: exclusive scan of bincnt[0..BINS) -> binptr, binhead
__global__ __launch_bounds__(256) void bin_scan(
    const int* __restrict__ bincnt, int* __restrict__ binptr,
    int* __restrict__ binhead, int* __restrict__ rowptr,
    int BINS, int N, int E)
{
    __shared__ int sl[256];
    const int t = threadIdx.x;
    int v[4];
    int s = 0;
    #pragma unroll
    for (int j = 0; j < 4; ++j) {
        int i = t * 4 + j;
        int c = (i < BINS) ? bincnt[i] : 0;
        v[j] = s;
        s += c;
    }
    sl[t] = s;
    __syncthreads();
    for (int off = 1; off < 256; off <<= 1) {
        int add = (t >= off) ? sl[t - off] : 0;
        __syncthreads();
        sl[t] += add;
        __syncthreads();
    }
    int excl = sl[t] - s;
    #pragma unroll
    for (int j = 0; j < 4; ++j) {
        int i = t * 4 + j;
        if (i < BINS) { binptr[i] = excl + v[j]; binhead[i] = excl + v[j]; }
    }
    if (t == 0) { binptr[BINS] = E; rowptr[N] = E; }
}

// partition edges into bin regions; packed = (dst&127)<<17 | src
__global__ __launch_bounds__(256) void partition_edges(
    const int* __restrict__ src, const int* __restrict__ dst,
    int* __restrict__ binhead, unsigned* __restrict__ packed_g, int E, int BINS)
{
    __shared__ int h[MAXBINS];
    __shared__ int goff[MAXBINS];
    __shared__ int fill[MAXBINS];
    const int t = threadIdx.x;
    for (int b = t; b < BINS; b += 256) { h[b] = 0; fill[b] = 0; }
    __syncthreads();
    int base = blockIdx.x * 4096;
    int eb[16];
    unsigned pk[16];
    #pragma unroll
    for (int j = 0; j < 16; ++j) {
        int e = base + j * 256 + t;
        if (e < E) {
            int d = dst[e], s = src[e];
            eb[j] = d >> BSH;
            pk[j] = ((unsigned)(d & ((1 << BSH) - 1)) << 17) | (unsigned)s;
            atomicAdd(&h[eb[j]], 1);
        } else eb[j] = -1;
    }
    __syncthreads();
    for (int b = t; b < BINS; b += 256)
        if (h[b]) goff[b] = atomicAdd(&binhead[b], h[b]);
    __syncthreads();
    #pragma unroll
    for (int j = 0; j < 16; ++j) {
        if (eb[j] >= 0) {
            int p = goff[eb[j]] + atomicAdd(&fill[eb[j]], 1);
            packed_g[p] = pk[j];
        }
    }
}

// one block per bin: per-node counts -> rowptr (coalesced), then place srcs
// (stored as BYTE OFFSETS into xbf: src*256) within the bin's L2-hot region.
__global__ __launch_bounds__(256) void bin_finalize(
    const unsigned* __restrict__ packed_g, const int* __restrict__ binptr,
    int* __restrict__ rowptr, int* __restrict__ srcs, int N)
{
    const int bin = blockIdx.x, t = threadIdx.x;
    const int beg = binptr[bin], end = binptr[bin + 1];
    const int node0 = bin << BSH;
    __shared__ int c[128];
    __shared__ int pf[128];
    __shared__ int hd[128];
    if (t < 128) c[t] = 0;
    __syncthreads();
    for (int i = beg + t; i < end; i += 256)
        atomicAdd(&c[packed_g[i] >> 17], 1);
    __syncthreads();
    if (t < 128) pf[t] = c[t];
    __syncthreads();
    for (int off = 1; off < 128; off <<= 1) {
        int v = 0;
        if (t < 128 && t >= off) v = pf[t - off];
        __syncthreads();
        if (t < 128) pf[t] += v;
        __syncthreads();
    }
    if (t < 128) {
        int node = node0 + t;
        if (node < N) {
            int r = beg + pf[t] - c[t];
            rowptr[node] = r;
            hd[t] = r;
        }
    }
    __syncthreads();
    for (int i = beg + t; i < end; i += 256) {
        unsigned p = packed_g[i];
        int dl = p >> 17;
        int s = p & 0x1FFFF;
        int pos = atomicAdd(&hd[dl], 1);
        srcs[pos] = s << 8;          // byte offset: src * 256 (bf16 row stride)
    }
}

// ===========================================================================
// Legacy CSR build (fallback only; srcs = raw indices)
// ===========================================================================
__global__ __launch_bounds__(256) void hist_kernel(
    const int* __restrict__ dst, int* __restrict__ cnt, int E)
{
    int e = blockIdx.x * 256 + threadIdx.x;
    if (e < E) atomicAdd(&cnt[dst[e]], 1);
}

__global__ __launch_bounds__(256) void scan1_kernel(
    const int* __restrict__ cnt, int* __restrict__ rowptr,
    int* __restrict__ blocksum, int N)
{
    __shared__ int sl[256];
    const int t = threadIdx.x;
    const int base = blockIdx.x * N_SCAN + t * 4;
    int v[4];
    int s = 0;
    #pragma unroll
    for (int j = 0; j < 4; ++j) {
        int i = base + j;
        int c = (i < N) ? cnt[i] : 0;
        v[j] = s;
        s += c;
    }
    sl[t] = s;
    __syncthreads();
    for (int off = 1; off < 256; off <<= 1) {
        int add = (t >= off) ? sl[t - off] : 0;
        __syncthreads();
        sl[t] += add;
        __syncthreads();
    }
    int incl = sl[t];
    int excl = incl - s;
    #pragma unroll
    for (int j = 0; j < 4; ++j) {
        int i = base + j;
        if (i < N) rowptr[i] = excl + v[j];
    }
    if (t == 255) blocksum[blockIdx.x] = incl;
}

__global__ void scan2_kernel(const int* __restrict__ blocksum,
                             int* __restrict__ blockoff, int nblk)
{
    if (threadIdx.x == 0 && blockIdx.x == 0) {
        int s = 0;
        for (int b = 0; b < nblk; ++b) { blockoff[b] = s; s += blocksum[b]; }
    }
}

__global__ __launch_bounds__(256) void scan3_kernel(
    int* __restrict__ rowptr, const int* __restrict__ blockoff,
    int* __restrict__ head, int N, int E)
{
    int i = blockIdx.x * 256 + threadIdx.x;
    if (i < N) {
        int r = rowptr[i] + blockoff[i >> 10];
        rowptr[i] = r;
        head[i] = r;
    } else if (i == N) {
        rowptr[N] = E;
    }
}

__global__ __launch_bounds__(256) void scatter_edges(
    const int* __restrict__ src, const int* __restrict__ dst,
    int* __restrict__ head, int* __restrict__ srcs, int E)
{
    int e = blockIdx.x * 256 + threadIdx.x;
    if (e < E) {
        int pos = atomicAdd(&head[dst[e]], 1);
        srcs[pos] = src[e];
    }
}

// ===========================================================================
// bf16 conversion
// ===========================================================================
__global__ __launch_bounds__(256) void convert_bf16(
    const float* __restrict__ x, unsigned short* __restrict__ xb, long long total)
{
    long long i = ((long long)blockIdx.x * 256 + threadIdx.x) * 8;
    if (i >= total) return;
    float4 f0 = *(const float4*)(x + i);
    float4 f1 = *(const float4*)(x + i + 4);
    us8 u;
    u[0] = f2bf(f0.x); u[1] = f2bf(f0.y); u[2] = f2bf(f0.z); u[3] = f2bf(f0.w);
    u[4] = f2bf(f1.x); u[5] = f2bf(f1.y); u[6] = f2bf(f1.z); u[7] = f2bf(f1.w);
    *(us8*)(xb + i) = u;
}

// ===========================================================================
// Weight pre-conversion, FRAGMENT-MAJOR: chunk c (16B) = B-fragment bytes for
// lane l = c&63 of (o-tile t = (c>>6)>>3, k-step s = (c>>6)&7):
// row o = t*16 + (l&15), bf16 k = s*32 + (l>>4)*8.
// ===========================================================================
__global__ __launch_bounds__(256) void convert_w_frag(
    const float* __restrict__ Wl, const float* __restrict__ Wr,
    unsigned short* __restrict__ wbf)
{
    int c = blockIdx.x * 256 + threadIdx.x;    // 0..4095
    if (c >= 4096) return;
    int l  = c & 63;
    int ts = c >> 6;
    int t  = ts >> 3, s = ts & 7;
    int o  = t * 16 + (l & 15);
    int k2 = s * 32 + (l >> 4) * 8;
    const float* srcw = (k2 < 128) ? (Wl + o * D + k2) : (Wr + o * D + (k2 - 128));
    float4 f0 = *(const float4*)(srcw);
    float4 f1 = *(const float4*)(srcw + 4);
    us8 u;
    u[0] = f2bf(f0.x); u[1] = f2bf(f0.y); u[2] = f2bf(f0.z); u[3] = f2bf(f0.w);
    u[4] = f2bf(f1.x); u[5] = f2bf(f1.y); u[6] = f2bf(f1.z); u[7] = f2bf(f1.w);
    ((us8*)wbf)[c] = u;
}

// ===========================================================================
// FUSED aggregate + matmul v2. Block = 16 nodes, 256 thr (4 waves).
// NEW: all 16 B-fragments (this wave's 2 o-tiles x 8 k-steps) are prefetched
// into registers AT KERNEL ENTRY and pinned with an empty asm consume, so
// their L2 latency hides under the ~60us aggregation phase. Phase 2 then has
// ZERO global loads: A from LDS/regs, B from regs, pure MFMA.
// ===========================================================================
__global__ __launch_bounds__(256) void fused_agg_mm(
    const unsigned short* __restrict__ xb, const int* __restrict__ rowptr,
    const int* __restrict__ srcs, const unsigned short* __restrict__ wfrag,
    const float* __restrict__ bl, float* __restrict__ out, int N)
{
    __shared__ unsigned short agg_lds[16][136];   // padded: row stride 272B
    const int tid  = threadIdx.x;
    const int lane = tid & 63;
    const int wv   = tid >> 6;          // 0..3
    const int m0   = blockIdx.x * 16;
    const int arow = lane & 15;
    const int kq   = lane >> 4;

    // ---- B-fragment prefetch: wave wv's o-tiles {2wv, 2wv+1} x 8 k-steps ----
    const s16x8* wf = (const s16x8*)wfrag;
    s16x8 bfr[16];
    #pragma unroll
    for (int s = 0; s < 8; ++s) {
        #pragma unroll
        for (int ti = 0; ti < 2; ++ti)
            bfr[s * 2 + ti] = wf[((wv * 2 + ti) * 8 + s) * 64 + lane];
    }
    // pin in registers (prevent the loads sinking past the barrier)
    #pragma unroll
    for (int i = 0; i < 16; ++i)
        asm volatile("" :: "v"(bfr[i]));

    // ---- x-fragment prefetch (K=128..255 half), independent of aggregation
    const int xrow = m0 + arow;
    const bool vr = (xrow < N);
    s16x8 xf[4];
    #pragma unroll
    for (int s = 0; s < 4; ++s) {
        s16x8 z = {0, 0, 0, 0, 0, 0, 0, 0};
        xf[s] = z;
        if (vr) xf[s] = *(const s16x8*)(xb + (size_t)xrow * D + s * 32 + kq * 8);
    }

    // ---- Phase 1: aggregation (4 nodes per wave, serial) ----
    const char* xbase = (const char*)xb;
    #pragma unroll
    for (int j = 0; j < 4; ++j) {
        const int nd = wv * 4 + j;
        const int node = m0 + nd;
        float accL = 0.f, accH = 0.f;
        if (node < N) {
            const int beg = rowptr[node], end = rowptr[node + 1];
            for (int b = beg; b < end; b += 64) {
                int idx = b + lane;
                int srcv = srcs[idx < end ? idx : end - 1];
                int cnt = end - b; if (cnt > 64) cnt = 64;
                int i = 0;
                for (; i + 8 <= cnt; i += 8) {
                    unsigned u[8];
                    #pragma unroll
                    for (int k = 0; k < 8; ++k) {
                        int so = __builtin_amdgcn_readlane(srcv, i + k);  // SGPR
                        u[k] = *(const unsigned*)(xbase + so + lane * 4);
                    }
                    #pragma unroll
                    for (int k = 0; k < 8; ++k) {
                        accL += __uint_as_float(u[k] << 16);
                        accH += __uint_as_float(u[k] & 0xffff0000u);
                    }
                }
                for (; i < cnt; ++i) {
                    int so = __builtin_amdgcn_readlane(srcv, i);
                    unsigned u = *(const unsigned*)(xbase + so + lane * 4);
                    accL += __uint_as_float(u << 16);
                    accH += __uint_as_float(u & 0xffff0000u);
                }
            }
            float inv = 1.0f / fmaxf((float)(end - beg), 1.0f);
            accL *= inv; accH *= inv;
        }
        unsigned lo = f2bf(accL);
        unsigned hi = f2bf(accH);
        *(unsigned*)&agg_lds[nd][lane * 2] = lo | (hi << 16);
    }
    __syncthreads();

    // ---- Phase 2: MFMA (wave wv: o-tiles 2wv, 2wv+1) — no global loads ----
    f32x4 acc[2] = {};
    #pragma unroll
    for (int s = 0; s < 8; ++s) {
        s16x8 af;
        if (s < 4) af = *(const s16x8*)&agg_lds[arow][s * 32 + kq * 8];
        else       af = xf[s - 4];
        #pragma unroll
        for (int ti = 0; ti < 2; ++ti) {
            acc[ti] = __builtin_amdgcn_mfma_f32_16x16x32_bf16(af, bfr[s * 2 + ti], acc[ti], 0, 0, 0);
        }
    }

    // ---- Epilogue: bias + LeakyReLU ----
    const int crow = (lane >> 4) * 4;
    const int ccol = lane & 15;
    #pragma unroll
    for (int ti = 0; ti < 2; ++ti) {
        int col = (wv * 2 + ti) * 16 + ccol;
        float bb = bl[col];
        #pragma unroll
        for (int r = 0; r < 4; ++r) {
            int row = m0 + crow + r;
            if (row < N) {
                float vv = acc[ti][r] + bb;
                out[(size_t)row * D + col] = vv > 0.f ? vv : 0.2f * vv;
            }
        }
    }
}

// ===========================================================================
// Fallback path kernels (legacy, proven)
// ===========================================================================
__global__ __launch_bounds__(256) void aggregate_bf16(
    const unsigned short* __restrict__ xb, const int* __restrict__ rowptr,
    const int* __restrict__ srcs, unsigned short* __restrict__ aggb, int N)
{
    int wid  = (blockIdx.x * 256 + threadIdx.x) >> 6;
    int lane = threadIdx.x & 63;
    if (wid >= N) return;
    int beg = rowptr[wid], end = rowptr[wid + 1];
    const int q  = lane >> 4;
    const int sl = lane & 15;

    float acc[8] = {};
    int e = beg;
    for (; e + 8 <= end; e += 8) {
        int s0 = srcs[e + q];
        int s1 = srcs[e + 4 + q];
        us8 v0 = *(const us8*)(xb + (long long)s0 * D + sl * 8);
        us8 v1 = *(const us8*)(xb + (long long)s1 * D + sl * 8);
        #pragma unroll
        for (int j = 0; j < 8; ++j) acc[j] += bf2f(v0[j]);
        #pragma unroll
        for (int j = 0; j < 8; ++j) acc[j] += bf2f(v1[j]);
    }
    for (; e < end; e += 4) {
        int ee = e + q;
        if (ee < end) {
            int s0 = srcs[ee];
            us8 v0 = *(const us8*)(xb + (long long)s0 * D + sl * 8);
            #pragma unroll
            for (int j = 0; j < 8; ++j) acc[j] += bf2f(v0[j]);
        }
    }
    #pragma unroll
    for (int j = 0; j < 8; ++j) {
        acc[j] += __shfl_xor(acc[j], 16, 64);
        acc[j] += __shfl_xor(acc[j], 32, 64);
    }
    float inv = 1.0f / fmaxf((float)(end - beg), 1.0f);
    if (q == 0) {
        us8 u;
        #pragma unroll
        for (int j = 0; j < 8; ++j) u[j] = f2bf(acc[j] * inv);
        *(us8*)(aggb + (long long)wid * D + sl * 8) = u;
    }
}

__global__ __launch_bounds__(256) void mm_mfma(
    const unsigned short* __restrict__ xb,
    const unsigned short* __restrict__ aggb,
    const float* __restrict__ Wl, const float* __restrict__ bl,
    const float* __restrict__ Wr,
    float* __restrict__ out, int N)
{
    __shared__ char wlds[64 * 1024];
    const int tid = threadIdx.x;

    for (int c = tid; c < 4096; c += 256) {
        int byte = c * 16;
        int o  = byte >> 9;
        int k2 = (byte & 511) >> 1;
        const float* srcw = (k2 < 128) ? (Wl + o * D + k2) : (Wr + o * D + (k2 - 128));
        float4 f0 = *(const float4*)(srcw);
        float4 f1 = *(const float4*)(srcw + 4);
        us8 u;
        u[0] = f2bf(f0.x); u[1] = f2bf(f0.y); u[2] = f2bf(f0.z); u[3] = f2bf(f0.w);
        u[4] = f2bf(f1.x); u[5] = f2bf(f1.y); u[6] = f2bf(f1.z); u[7] = f2bf(f1.w);
        *(us8*)(wlds + (byte ^ ((o & 7) << 4))) = u;
    }
    __syncthreads();

    const int lane = tid & 63;
    const int wv   = tid >> 6;
    const long long m0 = (long long)blockIdx.x * 64 + wv * 16;
    const int arow = lane & 15;
    const int kq   = lane >> 4;
    const long long mrow = m0 + arow;
    const bool valid = (mrow < N);
    const unsigned short* aP = aggb + mrow * D + kq * 8;
    const unsigned short* xP = xb   + mrow * D + kq * 8;

    f32x4 acc[8] = {};

    #pragma unroll
    for (int s = 0; s < 8; ++s) {
        s16x8 afrag = {0, 0, 0, 0, 0, 0, 0, 0};
        if (valid) {
            const unsigned short* ap = (s < 4) ? (aP + s * 32) : (xP + (s - 4) * 32);
            afrag = *(const s16x8*)ap;
        }
        #pragma unroll
        for (int t = 0; t < 8; ++t) {
            int o = t * 16 + arow;
            int boff = (o << 9) + s * 64 + kq * 16;
            boff ^= (o & 7) << 4;
            s16x8 bfrag = *(const s16x8*)(wlds + boff);
            acc[t] = __builtin_amdgcn_mfma_f32_16x16x32_bf16(afrag, bfrag, acc[t], 0, 0, 0);
        }
    }

    const int crow = (lane >> 4) * 4;
    const int ccol = lane & 15;
    #pragma unroll
    for (int t = 0; t < 8; ++t) {
        int col = t * 16 + ccol;
        float bb = bl[col];
        #pragma unroll
        for (int r = 0; r < 4; ++r) {
            long long row = m0 + crow + r;
            if (row < N) {
                float v = acc[t][r] + bb;
                out[row * D + col] = v > 0.f ? v : 0.2f * v;
            }
        }
    }
}

__global__ __launch_bounds__(256) void aggregate_f32(
    const float* __restrict__ x, const int* __restrict__ rowptr,
    const int* __restrict__ srcs, float* __restrict__ out, int N)
{
    int wid  = (blockIdx.x * 256 + threadIdx.x) >> 6;
    int lane = threadIdx.x & 63;
    if (wid >= N) return;
    int beg = rowptr[wid], end = rowptr[wid + 1];
    const float2* x2 = (const float2*)x;
    float ax = 0.f, ay = 0.f;
    int e = beg;
    for (; e + 4 <= end; e += 4) {
        int s0 = srcs[e], s1 = srcs[e + 1], s2 = srcs[e + 2], s3 = srcs[e + 3];
        float2 v0 = x2[(long long)s0 * 64 + lane];
        float2 v1 = x2[(long long)s1 * 64 + lane];
        float2 v2 = x2[(long long)s2 * 64 + lane];
        float2 v3 = x2[(long long)s3 * 64 + lane];
        ax += v0.x + v1.x + v2.x + v3.x;
        ay += v0.y + v1.y + v2.y + v3.y;
    }
    for (; e < end; ++e) {
        float2 v = x2[(long long)srcs[e] * 64 + lane];
        ax += v.x; ay += v.y;
    }
    float inv = 1.0f / fmaxf((float)(end - beg), 1.0f);
    float2 o; o.x = ax * inv; o.y = ay * inv;
    ((float2*)out)[(long long)wid * 64 + lane] = o;
}

#define MT 32
#define KT 32
__global__ __launch_bounds__(256) void sage_mm_f32(
    const float* __restrict__ x, const float* __restrict__ Wl,
    const float* __restrict__ bl, const float* __restrict__ Wr,
    float* __restrict__ out, int N)
{
    __shared__ __align__(16) float a_s[KT][MT + 4];
    __shared__ __align__(16) float x_s[KT][MT + 4];
    __shared__ __align__(16) float wl_s[KT][D + 4];
    __shared__ __align__(16) float wr_s[KT][D + 4];

    const int tid = threadIdx.x;
    const int tx = tid & 31;
    const int ty = tid >> 5;
    const int node0 = blockIdx.x * MT;

    float acc[4][4] = {};

    for (int k0 = 0; k0 < D; k0 += KT) {
        __syncthreads();
        for (int i = tid; i < MT * KT; i += 256) {
            int n = i >> 5, kk = i & 31;
            int node = node0 + n;
            float av = 0.f, xv = 0.f;
            if (node < N) {
                av = out[(long long)node * D + k0 + kk];
                xv = x[(long long)node * D + k0 + kk];
            }
            a_s[kk][n] = av;
            x_s[kk][n] = xv;
        }
        for (int i = tid; i < D * KT; i += 256) {
            int o = i >> 5, kk = i & 31;
            wl_s[kk][o] = Wl[o * D + k0 + kk];
            wr_s[kk][o] = Wr[o * D + k0 + kk];
        }
        __syncthreads();
        #pragma unroll
        for (int kk = 0; kk < KT; ++kk) {
            float4 a4 = *(const float4*)&a_s[kk][ty * 4];
            float4 x4 = *(const float4*)&x_s[kk][ty * 4];
            float4 l4 = *(const float4*)&wl_s[kk][tx * 4];
            float4 r4 = *(const float4*)&wr_s[kk][tx * 4];
            float an[4] = {a4.x, a4.y, a4.z, a4.w};
            float xn[4] = {x4.x, x4.y, x4.z, x4.w};
            float lo[4] = {l4.x, l4.y, l4.z, l4.w};
            float ro[4] = {r4.x, r4.y, r4.z, r4.w};
            #pragma unroll
            for (int n = 0; n < 4; ++n)
                #pragma unroll
                for (int o = 0; o < 4; ++o)
                    acc[n][o] += an[n] * lo[o] + xn[n] * ro[o];
        }
    }

    float4 b4 = *(const float4*)&bl[tx * 4];
    float bb[4] = {b4.x, b4.y, b4.z, b4.w};
    #pragma unroll
    for (int n = 0; n < 4; ++n) {
        int node = node0 + ty * 4 + n;
        if (node < N) {
            float4 o4;
            float* po = (float*)&o4;
            #pragma unroll
            for (int o = 0; o < 4; ++o) {
                float v = acc[n][o] + bb[o];
                po[o] = v > 0.f ? v : 0.2f * v;
            }
            *(float4*)&out[(long long)node * D + tx * 4] = o4;
        }
    }
}

extern "C" void kernel_launch(void* const* d_in, const int* in_sizes, int n_in,
                              void* d_out, int out_size, void* d_ws, size_t ws_size,
                              hipStream_t stream)
{
    const float* x  = (const float*)d_in[0];
    const int*   ei = (const int*)d_in[1];   // [2, E]: row0=src, row1=dst
    const float* Wl = (const float*)d_in[2];
    const float* bl = (const float*)d_in[3];
    const float* Wr = (const float*)d_in[4];

    const int E = in_sizes[1] / 2;
    const int N = out_size / D;
    const int* src = ei;
    const int* dst = ei + E;
    float* out = (float*)d_out;
    const int BINS = (N + (1 << BSH) - 1) >> BSH;

    // workspace layout (fused path: no aggb needed)
    size_t off = 0;
    auto take = [&](size_t bytes) { size_t p = off; off = (off + bytes + 255) & ~(size_t)255; return p; };
    char* w = (char*)d_ws;
    int* rowptr   = (int*)(w + take((size_t)(N + 1) * 4));
    int* srcs     = (int*)(w + take((size_t)E * 4));
    int* bincnt   = (int*)(w + take((size_t)BINS * 4));
    int* binptr   = (int*)(w + take((size_t)(BINS + 1) * 4));
    int* binhead  = (int*)(w + take((size_t)BINS * 4));
    unsigned* packed = (unsigned*)(w + take((size_t)E * 4));
    unsigned short* wbf = (unsigned short*)(w + take(64 * 1024));
    unsigned short* xbf = (unsigned short*)(w + take((size_t)N * D * 2));
    size_t fused_needed = off;

    const bool fused_ok = (BINS <= MAXBINS) && (N < (1 << 17)) && (ws_size >= fused_needed);

    if (fused_ok) {
        // --- weight pre-conversion to fragment-major bf16 (one-shot) ---
        convert_w_frag<<<16, 256, 0, stream>>>(Wl, Wr, wbf);

        // --- binned CSR build (srcs = byte offsets) ---
        hipMemsetAsync(bincnt, 0, (size_t)BINS * 4, stream);
        int pb = (E + 4095) / 4096;
        bin_hist<<<pb, 256, 0, stream>>>(dst, bincnt, E, BINS);
        bin_scan<<<1, 256, 0, stream>>>(bincnt, binptr, binhead, rowptr, BINS, N, E);
        partition_edges<<<pb, 256, 0, stream>>>(src, dst, binhead, packed, E, BINS);
        bin_finalize<<<BINS, 256, 0, stream>>>(packed, binptr, rowptr, srcs, N);

        // --- bf16 convert + fused aggregate+matmul ---
        long long total = (long long)N * D;
        int cb = (int)((total / 8 + 255) / 256);
        convert_bf16<<<cb, 256, 0, stream>>>(x, xbf, total);
        int fb = (N + 15) / 16;
        fused_agg_mm<<<fb, 256, 0, stream>>>(xbf, rowptr, srcs, wbf, bl, out, N);
        return;
    }

    // ---------------- fallback: legacy CSR build + split kernels ----------------
    off = 0;
    int* cnt    = (int*)(w + take((size_t)N * 4));
    rowptr      = (int*)(w + take((size_t)(N + 1) * 4));
    int* head   = (int*)(w + take((size_t)N * 4));
    int* blocksum = (int*)(w + take(4096));
    int* blockoff = (int*)(w + take(4096));
    srcs        = (int*)(w + take((size_t)E * 4));
    size_t base_needed = off;
    xbf   = (unsigned short*)(w + take((size_t)N * D * 2));
    unsigned short* aggbf = (unsigned short*)(w + take((size_t)N * D * 2));
    size_t bf16_needed = off;

    hipMemsetAsync(cnt, 0, (size_t)N * 4, stream);
    const int eb = (E + 255) / 256;
    hist_kernel<<<eb, 256, 0, stream>>>(dst, cnt, E);
    const int nblk = (N + N_SCAN - 1) / N_SCAN;
    scan1_kernel<<<nblk, 256, 0, stream>>>(cnt, rowptr, blocksum, N);
    scan2_kernel<<<1, 64, 0, stream>>>(blocksum, blockoff, nblk);
    scan3_kernel<<<(N + 1 + 255) / 256, 256, 0, stream>>>(rowptr, blockoff, head, N, E);
    scatter_edges<<<eb, 256, 0, stream>>>(src, dst, head, srcs, E);

    if (ws_size >= bf16_needed) {
        long long total = (long long)N * D;
        int cb = (int)((total / 8 + 255) / 256);
        convert_bf16<<<cb, 256, 0, stream>>>(x, xbf, total);
        int ab = (N * 64 + 255) / 256;
        aggregate_bf16<<<ab, 256, 0, stream>>>(xbf, rowptr, srcs, aggbf, N);
        int mb = (N + 63) / 64;
        mm_mfma<<<mb, 256, 0, stream>>>(xbf, aggbf, Wl, bl, Wr, out, N);
    } else {
        (void)base_needed;
        int ab = (N * 64 + 255) / 256;
        aggregate_f32<<<ab, 256, 0, stream>>>(x, rowptr, srcs, out, N);
        sage_mm_f32<<<(N + MT - 1) / MT, 256, 0, stream>>>(x, Wl, bl, Wr, out, N);
    }
}

// Round 17
// 158.815 us; speedup vs baseline: 1.3637x; 1.3637x over previous
//
#include <hip/hip_runtime.h>

#define D 128
#define N_SCAN 1024
#define BSH 7            // 128 nodes per bin
#define MAXBINS 1024     // supports N <= 131072 (also the src<2^17 packing limit)

typedef float  f32x4  __attribute__((ext_vector_type(4)));
typedef short  s16x8  __attribute__((ext_vector_type(8)));   // 8 bf16 (4 VGPRs)
typedef unsigned short us8 __attribute__((ext_vector_type(8)));

__device__ __forceinline__ unsigned short f2bf(float f) {
    unsigned b = __float_as_uint(f);
    return (unsigned short)((b + 0x7fffu + ((b >> 16) & 1u)) >> 16);  // RTNE
}
__device__ __forceinline__ float bf2f(unsigned short u) {
    return __uint_as_float((unsigned)u << 16);
}

// ===========================================================================
// PREP (one dispatch, three independent roles by blockIdx range):
//   [0, cb)          : x f32 -> bf16 convert
//   [cb, cb+pb)      : bin histogram of dst
//   [cb+pb, +16)     : weight f32 -> bf16 fragment-major convert
// Overlaps the small CSR-prep kernels under the big convert.
// ===========================================================================
__global__ __launch_bounds__(256) void prep_combined(
    const float* __restrict__ x, unsigned short* __restrict__ xbf, long long total,
    const int* __restrict__ dst, int* __restrict__ bincnt, int E, int BINS,
    const float* __restrict__ Wl, const float* __restrict__ Wr,
    unsigned short* __restrict__ wbf, int cb, int pb)
{
    __shared__ int h[MAXBINS];
    const int bid = blockIdx.x;
    if (bid < cb) {
        // ---- convert_bf16 role ----
        long long i = ((long long)bid * 256 + threadIdx.x) * 8;
        if (i >= total) return;
        float4 f0 = *(const float4*)(x + i);
        float4 f1 = *(const float4*)(x + i + 4);
        us8 u;
        u[0] = f2bf(f0.x); u[1] = f2bf(f0.y); u[2] = f2bf(f0.z); u[3] = f2bf(f0.w);
        u[4] = f2bf(f1.x); u[5] = f2bf(f1.y); u[6] = f2bf(f1.z); u[7] = f2bf(f1.w);
        *(us8*)(xbf + i) = u;
    } else if (bid < cb + pb) {
        // ---- bin_hist role ----
        const int hb = bid - cb;
        for (int b = threadIdx.x; b < BINS; b += 256) h[b] = 0;
        __syncthreads();
        int base = hb * 4096;
        #pragma unroll
        for (int j = 0; j < 16; ++j) {
            int e = base + j * 256 + threadIdx.x;
            if (e < E) atomicAdd(&h[dst[e] >> BSH], 1);
        }
        __syncthreads();
        for (int b = threadIdx.x; b < BINS; b += 256)
            if (h[b]) atomicAdd(&bincnt[b], h[b]);
    } else {
        // ---- convert_w_frag role ----
        int c = (bid - cb - pb) * 256 + threadIdx.x;    // 0..4095
        if (c >= 4096) return;
        int l  = c & 63;
        int ts = c >> 6;
        int t  = ts >> 3, s = ts & 7;
        int o  = t * 16 + (l & 15);
        int k2 = s * 32 + (l >> 4) * 8;
        const float* srcw = (k2 < 128) ? (Wl + o * D + k2) : (Wr + o * D + (k2 - 128));
        float4 f0 = *(const float4*)(srcw);
        float4 f1 = *(const float4*)(srcw + 4);
        us8 u;
        u[0] = f2bf(f0.x); u[1] = f2bf(f0.y); u[2] = f2bf(f0.z); u[3] = f2bf(f0.w);
        u[4] = f2bf(f1.x); u[5] = f2bf(f1.y); u[6] = f2bf(f1.z); u[7] = f2bf(f1.w);
        ((us8*)wbf)[c] = u;
    }
}

// single block: exclusive scan of bincnt[0..BINS) -> binptr, binhead
__global__ __launch_bounds__(256) void bin_scan(
    const int* __restrict__ bincnt, int* __restrict__ binptr,
    int* __restrict__ binhead, int* __restrict__ rowptr,
    int BINS, int N, int E)
{
    __shared__ int sl[256];
    const int t = threadIdx.x;
    int v[4];
    int s = 0;
    #pragma unroll
    for (int j = 0; j < 4; ++j) {
        int i = t * 4 + j;
        int c = (i < BINS) ? bincnt[i] : 0;
        v[j] = s;
        s += c;
    }
    sl[t] = s;
    __syncthreads();
    for (int off = 1; off < 256; off <<= 1) {
        int add = (t >= off) ? sl[t - off] : 0;
        __syncthreads();
        sl[t] += add;
        __syncthreads();
    }
    int excl = sl[t] - s;
    #pragma unroll
    for (int j = 0; j < 4; ++j) {
        int i = t * 4 + j;
        if (i < BINS) { binptr[i] = excl + v[j]; binhead[i] = excl + v[j]; }
    }
    if (t == 0) { binptr[BINS] = E; rowptr[N] = E; }
}

// partition edges into bin regions; packed = (dst&127)<<17 | src
__global__ __launch_bounds__(256) void partition_edges(
    const int* __restrict__ src, const int* __restrict__ dst,
    int* __restrict__ binhead, unsigned* __restrict__ packed_g, int E, int BINS)
{
    __shared__ int h[MAXBINS];
    __shared__ int goff[MAXBINS];
    __shared__ int fill[MAXBINS];
    const int t = threadIdx.x;
    for (int b = t; b < BINS; b += 256) { h[b] = 0; fill[b] = 0; }
    __syncthreads();
    int base = blockIdx.x * 4096;
    int eb[16];
    unsigned pk[16];
    #pragma unroll
    for (int j = 0; j < 16; ++j) {
        int e = base + j * 256 + t;
        if (e < E) {
            int d = dst[e], s = src[e];
            eb[j] = d >> BSH;
            pk[j] = ((unsigned)(d & ((1 << BSH) - 1)) << 17) | (unsigned)s;
            atomicAdd(&h[eb[j]], 1);
        } else eb[j] = -1;
    }
    __syncthreads();
    for (int b = t; b < BINS; b += 256)
        if (h[b]) goff[b] = atomicAdd(&binhead[b], h[b]);
    __syncthreads();
    #pragma unroll
    for (int j = 0; j < 16; ++j) {
        if (eb[j] >= 0) {
            int p = goff[eb[j]] + atomicAdd(&fill[eb[j]], 1);
            packed_g[p] = pk[j];
        }
    }
}

// one block per bin: per-node counts -> rowptr (coalesced), then place srcs
// (stored as BYTE OFFSETS into xbf: src*256) within the bin's L2-hot region.
__global__ __launch_bounds__(256) void bin_finalize(
    const unsigned* __restrict__ packed_g, const int* __restrict__ binptr,
    int* __restrict__ rowptr, int* __restrict__ srcs, int N)
{
    const int bin = blockIdx.x, t = threadIdx.x;
    const int beg = binptr[bin], end = binptr[bin + 1];
    const int node0 = bin << BSH;
    __shared__ int c[128];
    __shared__ int pf[128];
    __shared__ int hd[128];
    if (t < 128) c[t] = 0;
    __syncthreads();
    for (int i = beg + t; i < end; i += 256)
        atomicAdd(&c[packed_g[i] >> 17], 1);
    __syncthreads();
    if (t < 128) pf[t] = c[t];
    __syncthreads();
    for (int off = 1; off < 128; off <<= 1) {
        int v = 0;
        if (t < 128 && t >= off) v = pf[t - off];
        __syncthreads();
        if (t < 128) pf[t] += v;
        __syncthreads();
    }
    if (t < 128) {
        int node = node0 + t;
        if (node < N) {
            int r = beg + pf[t] - c[t];
            rowptr[node] = r;
            hd[t] = r;
        }
    }
    __syncthreads();
    for (int i = beg + t; i < end; i += 256) {
        unsigned p = packed_g[i];
        int dl = p >> 17;
        int s = p & 0x1FFFF;
        int pos = atomicAdd(&hd[dl], 1);
        srcs[pos] = s << 8;          // byte offset: src * 256 (bf16 row stride)
    }
}

// ===========================================================================
// Legacy CSR build (fallback only; srcs = raw indices)
// ===========================================================================
__global__ __launch_bounds__(256) void hist_kernel(
    const int* __restrict__ dst, int* __restrict__ cnt, int E)
{
    int e = blockIdx.x * 256 + threadIdx.x;
    if (e < E) atomicAdd(&cnt[dst[e]], 1);
}

__global__ __launch_bounds__(256) void scan1_kernel(
    const int* __restrict__ cnt, int* __restrict__ rowptr,
    int* __restrict__ blocksum, int N)
{
    __shared__ int sl[256];
    const int t = threadIdx.x;
    const int base = blockIdx.x * N_SCAN + t * 4;
    int v[4];
    int s = 0;
    #pragma unroll
    for (int j = 0; j < 4; ++j) {
        int i = base + j;
        int c = (i < N) ? cnt[i] : 0;
        v[j] = s;
        s += c;
    }
    sl[t] = s;
    __syncthreads();
    for (int off = 1; off < 256; off <<= 1) {
        int add = (t >= off) ? sl[t - off] : 0;
        __syncthreads();
        sl[t] += add;
        __syncthreads();
    }
    int incl = sl[t];
    int excl = incl - s;
    #pragma unroll
    for (int j = 0; j < 4; ++j) {
        int i = base + j;
        if (i < N) rowptr[i] = excl + v[j];
    }
    if (t == 255) blocksum[blockIdx.x] = incl;
}

__global__ void scan2_kernel(const int* __restrict__ blocksum,
                             int* __restrict__ blockoff, int nblk)
{
    if (threadIdx.x == 0 && blockIdx.x == 0) {
        int s = 0;
        for (int b = 0; b < nblk; ++b) { blockoff[b] = s; s += blocksum[b]; }
    }
}

__global__ __launch_bounds__(256) void scan3_kernel(
    int* __restrict__ rowptr, const int* __restrict__ blockoff,
    int* __restrict__ head, int N, int E)
{
    int i = blockIdx.x * 256 + threadIdx.x;
    if (i < N) {
        int r = rowptr[i] + blockoff[i >> 10];
        rowptr[i] = r;
        head[i] = r;
    } else if (i == N) {
        rowptr[N] = E;
    }
}

__global__ __launch_bounds__(256) void scatter_edges(
    const int* __restrict__ src, const int* __restrict__ dst,
    int* __restrict__ head, int* __restrict__ srcs, int E)
{
    int e = blockIdx.x * 256 + threadIdx.x;
    if (e < E) {
        int pos = atomicAdd(&head[dst[e]], 1);
        srcs[pos] = src[e];
    }
}

// ===========================================================================
// bf16 conversion (fallback path)
// ===========================================================================
__global__ __launch_bounds__(256) void convert_bf16(
    const float* __restrict__ x, unsigned short* __restrict__ xb, long long total)
{
    long long i = ((long long)blockIdx.x * 256 + threadIdx.x) * 8;
    if (i >= total) return;
    float4 f0 = *(const float4*)(x + i);
    float4 f1 = *(const float4*)(x + i + 4);
    us8 u;
    u[0] = f2bf(f0.x); u[1] = f2bf(f0.y); u[2] = f2bf(f0.z); u[3] = f2bf(f0.w);
    u[4] = f2bf(f1.x); u[5] = f2bf(f1.y); u[6] = f2bf(f1.z); u[7] = f2bf(f1.w);
    *(us8*)(xb + i) = u;
}

// ===========================================================================
// FUSED aggregate + matmul (R15-proven form). Block = 16 nodes, 256 thr.
// Phase 1: wave wv aggregates nodes m0+wv*4..+3 (scalar-base row gathers),
//   packs bf16 agg rows into padded LDS [16][136].
// Phase 2: wave wv computes o-tiles {2wv, 2wv+1}: A s<4 from LDS, s>=4 from
//   xf regs prefetched at entry; B from L2-hot fragment-major wfrag.
// ===========================================================================
__global__ __launch_bounds__(256) void fused_agg_mm(
    const unsigned short* __restrict__ xb, const int* __restrict__ rowptr,
    const int* __restrict__ srcs, const unsigned short* __restrict__ wfrag,
    const float* __restrict__ bl, float* __restrict__ out, int N)
{
    __shared__ unsigned short agg_lds[16][136];   // padded: row stride 272B
    const int tid  = threadIdx.x;
    const int lane = tid & 63;
    const int wv   = tid >> 6;          // 0..3
    const int m0   = blockIdx.x * 16;
    const int arow = lane & 15;
    const int kq   = lane >> 4;

    // ---- x-fragment prefetch (K=128..255 half), independent of aggregation
    const int xrow = m0 + arow;
    const bool vr = (xrow < N);
    s16x8 xf[4];
    #pragma unroll
    for (int s = 0; s < 4; ++s) {
        s16x8 z = {0, 0, 0, 0, 0, 0, 0, 0};
        xf[s] = z;
        if (vr) xf[s] = *(const s16x8*)(xb + (size_t)xrow * D + s * 32 + kq * 8);
    }

    // ---- Phase 1: aggregation (4 nodes per wave, serial) ----
    const char* xbase = (const char*)xb;
    #pragma unroll
    for (int j = 0; j < 4; ++j) {
        const int nd = wv * 4 + j;
        const int node = m0 + nd;
        float accL = 0.f, accH = 0.f;
        if (node < N) {
            const int beg = rowptr[node], end = rowptr[node + 1];
            for (int b = beg; b < end; b += 64) {
                int idx = b + lane;
                int srcv = srcs[idx < end ? idx : end - 1];
                int cnt = end - b; if (cnt > 64) cnt = 64;
                int i = 0;
                for (; i + 8 <= cnt; i += 8) {
                    unsigned u[8];
                    #pragma unroll
                    for (int k = 0; k < 8; ++k) {
                        int so = __builtin_amdgcn_readlane(srcv, i + k);  // SGPR
                        u[k] = *(const unsigned*)(xbase + so + lane * 4);
                    }
                    #pragma unroll
                    for (int k = 0; k < 8; ++k) {
                        accL += __uint_as_float(u[k] << 16);
                        accH += __uint_as_float(u[k] & 0xffff0000u);
                    }
                }
                for (; i < cnt; ++i) {
                    int so = __builtin_amdgcn_readlane(srcv, i);
                    unsigned u = *(const unsigned*)(xbase + so + lane * 4);
                    accL += __uint_as_float(u << 16);
                    accH += __uint_as_float(u & 0xffff0000u);
                }
            }
            float inv = 1.0f / fmaxf((float)(end - beg), 1.0f);
            accL *= inv; accH *= inv;
        }
        unsigned lo = f2bf(accL);
        unsigned hi = f2bf(accH);
        *(unsigned*)&agg_lds[nd][lane * 2] = lo | (hi << 16);
    }
    __syncthreads();

    // ---- Phase 2: MFMA (wave wv: o-tiles 2wv, 2wv+1) ----
    const s16x8* wf = (const s16x8*)wfrag;
    f32x4 acc[2] = {};
    #pragma unroll
    for (int s = 0; s < 8; ++s) {
        s16x8 af;
        if (s < 4) af = *(const s16x8*)&agg_lds[arow][s * 32 + kq * 8];
        else       af = xf[s - 4];
        #pragma unroll
        for (int ti = 0; ti < 2; ++ti) {
            int t = wv * 2 + ti;
            s16x8 bf = wf[(t * 8 + s) * 64 + lane];   // 1KB coalesced, L2-hot
            acc[ti] = __builtin_amdgcn_mfma_f32_16x16x32_bf16(af, bf, acc[ti], 0, 0, 0);
        }
    }

    // ---- Epilogue: bias + LeakyReLU ----
    const int crow = (lane >> 4) * 4;
    const int ccol = lane & 15;
    #pragma unroll
    for (int ti = 0; ti < 2; ++ti) {
        int col = (wv * 2 + ti) * 16 + ccol;
        float bb = bl[col];
        #pragma unroll
        for (int r = 0; r < 4; ++r) {
            int row = m0 + crow + r;
            if (row < N) {
                float vv = acc[ti][r] + bb;
                out[(size_t)row * D + col] = vv > 0.f ? vv : 0.2f * vv;
            }
        }
    }
}

// ===========================================================================
// Fallback path kernels (legacy, proven)
// ===========================================================================
__global__ __launch_bounds__(256) void aggregate_bf16(
    const unsigned short* __restrict__ xb, const int* __restrict__ rowptr,
    const int* __restrict__ srcs, unsigned short* __restrict__ aggb, int N)
{
    int wid  = (blockIdx.x * 256 + threadIdx.x) >> 6;
    int lane = threadIdx.x & 63;
    if (wid >= N) return;
    int beg = rowptr[wid], end = rowptr[wid + 1];
    const int q  = lane >> 4;
    const int sl = lane & 15;

    float acc[8] = {};
    int e = beg;
    for (; e + 8 <= end; e += 8) {
        int s0 = srcs[e + q];
        int s1 = srcs[e + 4 + q];
        us8 v0 = *(const us8*)(xb + (long long)s0 * D + sl * 8);
        us8 v1 = *(const us8*)(xb + (long long)s1 * D + sl * 8);
        #pragma unroll
        for (int j = 0; j < 8; ++j) acc[j] += bf2f(v0[j]);
        #pragma unroll
        for (int j = 0; j < 8; ++j) acc[j] += bf2f(v1[j]);
    }
    for (; e < end; e += 4) {
        int ee = e + q;
        if (ee < end) {
            int s0 = srcs[ee];
            us8 v0 = *(const us8*)(xb + (long long)s0 * D + sl * 8);
            #pragma unroll
            for (int j = 0; j < 8; ++j) acc[j] += bf2f(v0[j]);
        }
    }
    #pragma unroll
    for (int j = 0; j < 8; ++j) {
        acc[j] += __shfl_xor(acc[j], 16, 64);
        acc[j] += __shfl_xor(acc[j], 32, 64);
    }
    float inv = 1.0f / fmaxf((float)(end - beg), 1.0f);
    if (q == 0) {
        us8 u;
        #pragma unroll
        for (int j = 0; j < 8; ++j) u[j] = f2bf(acc[j] * inv);
        *(us8*)(aggb + (long long)wid * D + sl * 8) = u;
    }
}

__global__ __launch_bounds__(256) void mm_mfma(
    const unsigned short* __restrict__ xb,
    const unsigned short* __restrict__ aggb,
    const float* __restrict__ Wl, const float* __restrict__ bl,
    const float* __restrict__ Wr,
    float* __restrict__ out, int N)
{
    __shared__ char wlds[64 * 1024];
    const int tid = threadIdx.x;

    for (int c = tid; c < 4096; c += 256) {
        int byte = c * 16;
        int o  = byte >> 9;
        int k2 = (byte & 511) >> 1;
        const float* srcw = (k2 < 128) ? (Wl + o * D + k2) : (Wr + o * D + (k2 - 128));
        float4 f0 = *(const float4*)(srcw);
        float4 f1 = *(const float4*)(srcw + 4);
        us8 u;
        u[0] = f2bf(f0.x); u[1] = f2bf(f0.y); u[2] = f2bf(f0.z); u[3] = f2bf(f0.w);
        u[4] = f2bf(f1.x); u[5] = f2bf(f1.y); u[6] = f2bf(f1.z); u[7] = f2bf(f1.w);
        *(us8*)(wlds + (byte ^ ((o & 7) << 4))) = u;
    }
    __syncthreads();

    const int lane = tid & 63;
    const int wv   = tid >> 6;
    const long long m0 = (long long)blockIdx.x * 64 + wv * 16;
    const int arow = lane & 15;
    const int kq   = lane >> 4;
    const long long mrow = m0 + arow;
    const bool valid = (mrow < N);
    const unsigned short* aP = aggb + mrow * D + kq * 8;
    const unsigned short* xP = xb   + mrow * D + kq * 8;

    f32x4 acc[8] = {};

    #pragma unroll
    for (int s = 0; s < 8; ++s) {
        s16x8 afrag = {0, 0, 0, 0, 0, 0, 0, 0};
        if (valid) {
            const unsigned short* ap = (s < 4) ? (aP + s * 32) : (xP + (s - 4) * 32);
            afrag = *(const s16x8*)ap;
        }
        #pragma unroll
        for (int t = 0; t < 8; ++t) {
            int o = t * 16 + arow;
            int boff = (o << 9) + s * 64 + kq * 16;
            boff ^= (o & 7) << 4;
            s16x8 bfrag = *(const s16x8*)(wlds + boff);
            acc[t] = __builtin_amdgcn_mfma_f32_16x16x32_bf16(afrag, bfrag, acc[t], 0, 0, 0);
        }
    }

    const int crow = (lane >> 4) * 4;
    const int ccol = lane & 15;
    #pragma unroll
    for (int t = 0; t < 8; ++t) {
        int col = t * 16 + ccol;
        float bb = bl[col];
        #pragma unroll
        for (int r = 0; r < 4; ++r) {
            long long row = m0 + crow + r;
            if (row < N) {
                float v = acc[t][r] + bb;
                out[row * D + col] = v > 0.f ? v : 0.2f * v;
            }
        }
    }
}

__global__ __launch_bounds__(256) void aggregate_f32(
    const float* __restrict__ x, const int* __restrict__ rowptr,
    const int* __restrict__ srcs, float* __restrict__ out, int N)
{
    int wid  = (blockIdx.x * 256 + threadIdx.x) >> 6;
    int lane = threadIdx.x & 63;
    if (wid >= N) return;
    int beg = rowptr[wid], end = rowptr[wid + 1];
    const float2* x2 = (const float2*)x;
    float ax = 0.f, ay = 0.f;
    int e = beg;
    for (; e + 4 <= end; e += 4) {
        int s0 = srcs[e], s1 = srcs[e + 1], s2 = srcs[e + 2], s3 = srcs[e + 3];
        float2 v0 = x2[(long long)s0 * 64 + lane];
        float2 v1 = x2[(long long)s1 * 64 + lane];
        float2 v2 = x2[(long long)s2 * 64 + lane];
        float2 v3 = x2[(long long)s3 * 64 + lane];
        ax += v0.x + v1.x + v2.x + v3.x;
        ay += v0.y + v1.y + v2.y + v3.y;
    }
    for (; e < end; ++e) {
        float2 v = x2[(long long)srcs[e] * 64 + lane];
        ax += v.x; ay += v.y;
    }
    float inv = 1.0f / fmaxf((float)(end - beg), 1.0f);
    float2 o; o.x = ax * inv; o.y = ay * inv;
    ((float2*)out)[(long long)wid * 64 + lane] = o;
}

#define MT 32
#define KT 32
__global__ __launch_bounds__(256) void sage_mm_f32(
    const float* __restrict__ x, const float* __restrict__ Wl,
    const float* __restrict__ bl, const float* __restrict__ Wr,
    float* __restrict__ out, int N)
{
    __shared__ __align__(16) float a_s[KT][MT + 4];
    __shared__ __align__(16) float x_s[KT][MT + 4];
    __shared__ __align__(16) float wl_s[KT][D + 4];
    __shared__ __align__(16) float wr_s[KT][D + 4];

    const int tid = threadIdx.x;
    const int tx = tid & 31;
    const int ty = tid >> 5;
    const int node0 = blockIdx.x * MT;

    float acc[4][4] = {};

    for (int k0 = 0; k0 < D; k0 += KT) {
        __syncthreads();
        for (int i = tid; i < MT * KT; i += 256) {
            int n = i >> 5, kk = i & 31;
            int node = node0 + n;
            float av = 0.f, xv = 0.f;
            if (node < N) {
                av = out[(long long)node * D + k0 + kk];
                xv = x[(long long)node * D + k0 + kk];
            }
            a_s[kk][n] = av;
            x_s[kk][n] = xv;
        }
        for (int i = tid; i < D * KT; i += 256) {
            int o = i >> 5, kk = i & 31;
            wl_s[kk][o] = Wl[o * D + k0 + kk];
            wr_s[kk][o] = Wr[o * D + k0 + kk];
        }
        __syncthreads();
        #pragma unroll
        for (int kk = 0; kk < KT; ++kk) {
            float4 a4 = *(const float4*)&a_s[kk][ty * 4];
            float4 x4 = *(const float4*)&x_s[kk][ty * 4];
            float4 l4 = *(const float4*)&wl_s[kk][tx * 4];
            float4 r4 = *(const float4*)&wr_s[kk][tx * 4];
            float an[4] = {a4.x, a4.y, a4.z, a4.w};
            float xn[4] = {x4.x, x4.y, x4.z, x4.w};
            float lo[4] = {l4.x, l4.y, l4.z, l4.w};
            float ro[4] = {r4.x, r4.y, r4.z, r4.w};
            #pragma unroll
            for (int n = 0; n < 4; ++n)
                #pragma unroll
                for (int o = 0; o < 4; ++o)
                    acc[n][o] += an[n] * lo[o] + xn[n] * ro[o];
        }
    }

    float4 b4 = *(const float4*)&bl[tx * 4];
    float bb[4] = {b4.x, b4.y, b4.z, b4.w};
    #pragma unroll
    for (int n = 0; n < 4; ++n) {
        int node = node0 + ty * 4 + n;
        if (node < N) {
            float4 o4;
            float* po = (float*)&o4;
            #pragma unroll
            for (int o = 0; o < 4; ++o) {
                float v = acc[n][o] + bb[o];
                po[o] = v > 0.f ? v : 0.2f * v;
            }
            *(float4*)&out[(long long)node * D + tx * 4] = o4;
        }
    }
}

extern "C" void kernel_launch(void* const* d_in, const int* in_sizes, int n_in,
                              void* d_out, int out_size, void* d_ws, size_t ws_size,
                              hipStream_t stream)
{
    const float* x  = (const float*)d_in[0];
    const int*   ei = (const int*)d_in[1];   // [2, E]: row0=src, row1=dst
    const float* Wl = (const float*)d_in[2];
    const float* bl = (const float*)d_in[3];
    const float* Wr = (const float*)d_in[4];

    const int E = in_sizes[1] / 2;
    const int N = out_size / D;
    const int* src = ei;
    const int* dst = ei + E;
    float* out = (float*)d_out;
    const int BINS = (N + (1 << BSH) - 1) >> BSH;

    // workspace layout (fused path: no aggb needed)
    size_t off = 0;
    auto take = [&](size_t bytes) { size_t p = off; off = (off + bytes + 255) & ~(size_t)255; return p; };
    char* w = (char*)d_ws;
    int* rowptr   = (int*)(w + take((size_t)(N + 1) * 4));
    int* srcs     = (int*)(w + take((size_t)E * 4));
    int* bincnt   = (int*)(w + take((size_t)BINS * 4));
    int* binptr   = (int*)(w + take((size_t)(BINS + 1) * 4));
    int* binhead  = (int*)(w + take((size_t)BINS * 4));
    unsigned* packed = (unsigned*)(w + take((size_t)E * 4));
    unsigned short* wbf = (unsigned short*)(w + take(64 * 1024));
    unsigned short* xbf = (unsigned short*)(w + take((size_t)N * D * 2));
    size_t fused_needed = off;

    const bool fused_ok = (BINS <= MAXBINS) && (N < (1 << 17)) && (ws_size >= fused_needed);

    if (fused_ok) {
        hipMemsetAsync(bincnt, 0, (size_t)BINS * 4, stream);

        // --- combined prep: x convert + bin hist + weight convert (1 dispatch)
        long long total = (long long)N * D;
        int cb = (int)((total / 8 + 255) / 256);
        int pb = (E + 4095) / 4096;
        prep_combined<<<cb + pb + 16, 256, 0, stream>>>(
            x, xbf, total, dst, bincnt, E, BINS, Wl, Wr, wbf, cb, pb);

        // --- CSR build chain ---
        bin_scan<<<1, 256, 0, stream>>>(bincnt, binptr, binhead, rowptr, BINS, N, E);
        partition_edges<<<pb, 256, 0, stream>>>(src, dst, binhead, packed, E, BINS);
        bin_finalize<<<BINS, 256, 0, stream>>>(packed, binptr, rowptr, srcs, N);

        // --- fused aggregate+matmul ---
        int fb = (N + 15) / 16;
        fused_agg_mm<<<fb, 256, 0, stream>>>(xbf, rowptr, srcs, wbf, bl, out, N);
        return;
    }

    // ---------------- fallback: legacy CSR build + split kernels ----------------
    off = 0;
    int* cnt    = (int*)(w + take((size_t)N * 4));
    rowptr      = (int*)(w + take((size_t)(N + 1) * 4));
    int* head   = (int*)(w + take((size_t)N * 4));
    int* blocksum = (int*)(w + take(4096));
    int* blockoff = (int*)(w + take(4096));
    srcs        = (int*)(w + take((size_t)E * 4));
    size_t base_needed = off;
    xbf   = (unsigned short*)(w + take((size_t)N * D * 2));
    unsigned short* aggbf = (unsigned short*)(w + take((size_t)N * D * 2));
    size_t bf16_needed = off;

    hipMemsetAsync(cnt, 0, (size_t)N * 4, stream);
    const int eb = (E + 255) / 256;
    hist_kernel<<<eb, 256, 0, stream>>>(dst, cnt, E);
    const int nblk = (N + N_SCAN - 1) / N_SCAN;
    scan1_kernel<<<nblk, 256, 0, stream>>>(cnt, rowptr, blocksum, N);
    scan2_kernel<<<1, 64, 0, stream>>>(blocksum, blockoff, nblk);
    scan3_kernel<<<(N + 1 + 255) / 256, 256, 0, stream>>>(rowptr, blockoff, head, N, E);
    scatter_edges<<<eb, 256, 0, stream>>>(src, dst, head, srcs, E);

    if (ws_size >= bf16_needed) {
        long long total = (long long)N * D;
        int cb = (int)((total / 8 + 255) / 256);
        convert_bf16<<<cb, 256, 0, stream>>>(x, xbf, total);
        int ab = (N * 64 + 255) / 256;
        aggregate_bf16<<<ab, 256, 0, stream>>>(xbf, rowptr, srcs, aggbf, N);
        int mb = (N + 63) / 64;
        mm_mfma<<<mb, 256, 0, stream>>>(xbf, aggbf, Wl, bl, Wr, out, N);
    } else {
        (void)base_needed;
        int ab = (N * 64 + 255) / 256;
        aggregate_f32<<<ab, 256, 0, stream>>>(x, rowptr, srcs, out, N);
        sage_mm_f32<<<(N + MT - 1) / MT, 256, 0, stream>>>(x, Wl, bl, Wr, out, N);
    }
}